// Round 1
// baseline (1864.375 us; speedup 1.0000x reference)
//
#include <hip/hip_runtime.h>

typedef unsigned short u16;
typedef unsigned int   u32;
typedef __attribute__((ext_vector_type(2))) unsigned int u32x2;
typedef __attribute__((ext_vector_type(4))) float f32x4;
typedef __attribute__((ext_vector_type(8))) short s16x8;
typedef __attribute__((ext_vector_type(4))) _Float16 f16x4;

#define B_   2
#define T_   2048
#define D_   4096
#define H_   32
#define HKV_ 8
#define HD_  128
#define NQKV 6144
#define M_   (B_*T_)   // 4096

__device__ __forceinline__ u16 f2bf(float f){
  u32 u = __float_as_uint(f);
  u += 0x7fffu + ((u >> 16) & 1u);
  return (u16)(u >> 16);
}
__device__ __forceinline__ float bf2f(u16 h){
  return __uint_as_float(((u32)h) << 16);
}
__device__ __forceinline__ void gload16(const void* g, void* l){
  __builtin_amdgcn_global_load_lds(
      (const __attribute__((address_space(1))) u32*)g,
      (__attribute__((address_space(3))) u32*)l, 16, 0, 0);
}

// ---------------- x: f32 -> bf16 ----------------
__global__ void k_convert_x(const float* __restrict__ in, u16* __restrict__ out){
  int i = blockIdx.x * 256 + threadIdx.x;      // each thread: 4 elems
  float4 v = reinterpret_cast<const float4*>(in)[i];
  u32 lo = (u32)f2bf(v.x) | ((u32)f2bf(v.y) << 16);
  u32 hi = (u32)f2bf(v.z) | ((u32)f2bf(v.w) << 16);
  u32x2 p; p.x = lo; p.y = hi;
  reinterpret_cast<u32x2*>(out)[i] = p;
}

// ---------------- W (K x N f32, k-major) -> Wt (N x K bf16, n-major) ----------------
__global__ void k_transpose_w(const float* __restrict__ in, u16* __restrict__ out,
                              int K, int N){
  __shared__ float tile[32][33];
  int n0 = blockIdx.x * 32, k0 = blockIdx.y * 32;
  int tx = threadIdx.x, ty = threadIdx.y;     // 32 x 8
  #pragma unroll
  for (int i = ty; i < 32; i += 8)
    tile[i][tx] = in[(size_t)(k0 + i) * N + n0 + tx];
  __syncthreads();
  #pragma unroll
  for (int i = ty; i < 32; i += 8)
    out[(size_t)(n0 + i) * K + k0 + tx] = f2bf(tile[tx][i]);
}

// ---------------- GEMM: C[M,N] = A[M,K](bf16) * Wt[N,K](bf16) ----------------
// 128x128 tile, BK=64, 256 threads (4 waves, 2x2 of 64x64), XOR-swizzled LDS.
template<int OUT_F32>
__global__ __launch_bounds__(256, 2) void k_gemm(
    const u16* __restrict__ A, const u16* __restrict__ Bt,
    void* __restrict__ Cv, int M, int N, int K)
{
  __shared__ __attribute__((aligned(16))) unsigned char smem[32768];
  unsigned char* As = smem;            // [128 rows][128 B]  (64 bf16/row)
  unsigned char* Bs = smem + 16384;
  const int tid = threadIdx.x;
  const int w = tid >> 6, l = tid & 63;
  const int m0 = blockIdx.y * 128, n0 = blockIdx.x * 128;
  const int wm = (w >> 1) * 64, wn = (w & 1) * 64;
  f32x4 acc[4][4];
  #pragma unroll
  for (int i = 0; i < 4; i++)
    #pragma unroll
    for (int j = 0; j < 4; j++)
      acc[i][j] = f32x4{0.f, 0.f, 0.f, 0.f};

  // source column pre-swizzle so linear global_load_lds dest == swizzled layout
  const int srcoff = 8 * ((l & 7) ^ ((l >> 3) & 7));  // elements within row
  const int subrow = l >> 3;

  for (int k0 = 0; k0 < K; k0 += 64) {
    if (k0) __syncthreads();
    #pragma unroll
    for (int i = 0; i < 4; i++) {
      int chunk = 4 * w + i;               // 16 chunks of 1KB per tile
      int row = chunk * 8 + subrow;
      gload16(A  + (size_t)(m0 + row) * K + k0 + srcoff, As + chunk * 1024);
      gload16(Bt + (size_t)(n0 + row) * K + k0 + srcoff, Bs + chunk * 1024);
    }
    asm volatile("s_waitcnt vmcnt(0)" ::: "memory");
    __syncthreads();
    #pragma unroll
    for (int kk = 0; kk < 2; kk++) {
      s16x8 a[4], b[4];
      const int co = kk * 64 + 16 * (l >> 4);
      #pragma unroll
      for (int mi = 0; mi < 4; mi++) {
        int r = wm + 16 * mi + (l & 15);
        a[mi] = *reinterpret_cast<const s16x8*>(As + r * 128 + (co ^ ((r & 7) << 4)));
      }
      #pragma unroll
      for (int ni = 0; ni < 4; ni++) {
        int r = wn + 16 * ni + (l & 15);
        b[ni] = *reinterpret_cast<const s16x8*>(Bs + r * 128 + (co ^ ((r & 7) << 4)));
      }
      #pragma unroll
      for (int mi = 0; mi < 4; mi++)
        #pragma unroll
        for (int ni = 0; ni < 4; ni++)
          acc[mi][ni] = __builtin_amdgcn_mfma_f32_16x16x32_bf16(a[mi], b[ni], acc[mi][ni], 0, 0, 0);
    }
  }
  const int g = l >> 4, c = l & 15;
  #pragma unroll
  for (int mi = 0; mi < 4; mi++)
    #pragma unroll
    for (int ni = 0; ni < 4; ni++)
      #pragma unroll
      for (int r = 0; r < 4; r++) {
        int m = m0 + wm + 16 * mi + 4 * g + r;
        int n = n0 + wn + 16 * ni + c;
        float v = acc[mi][ni][r];
        if (OUT_F32) reinterpret_cast<float*>(Cv)[(size_t)m * N + n] = v;
        else         reinterpret_cast<u16*>(Cv)[(size_t)m * N + n] = f2bf(v);
      }
}

// ---------------- RoPE on Q (in place, cols 0..4095 of C1) ----------------
__global__ void k_rope_q(u16* C1, const float* __restrict__ fc, const float* __restrict__ fs){
  int idx = blockIdx.x * 256 + threadIdx.x;   // M_ * 2048 pairs
  int m = idx >> 11, p = idx & 2047;
  int h = p >> 6, i = p & 63;
  int t = m & (T_ - 1);
  u32* ptr = reinterpret_cast<u32*>(C1 + (size_t)m * NQKV + h * HD_ + 2 * i);
  u32 u = *ptr;
  float x0 = __uint_as_float(u << 16);
  float x1 = __uint_as_float(u & 0xffff0000u);
  float cc = fc[t * 64 + i], ss = fs[t * 64 + i];
  float o0 = x0 * cc - x1 * ss;
  float o1 = x0 * ss + x1 * cc;
  *ptr = (u32)f2bf(o0) | ((u32)f2bf(o1) << 16);
}

// ---------------- RoPE on K + rearrange to [B][HKV][T][HD] ----------------
__global__ void k_rope_k(const u16* __restrict__ C1, const float* __restrict__ fc,
                         const float* __restrict__ fs, u16* __restrict__ Kb){
  int idx = blockIdx.x * 256 + threadIdx.x;   // M_ * 512 pairs
  int m = idx >> 9, p = idx & 511;
  int kh = p >> 6, i = p & 63;
  int b = m >> 11, t = m & (T_ - 1);
  u32 u = *reinterpret_cast<const u32*>(C1 + (size_t)m * NQKV + D_ + kh * HD_ + 2 * i);
  float x0 = __uint_as_float(u << 16);
  float x1 = __uint_as_float(u & 0xffff0000u);
  float cc = fc[t * 64 + i], ss = fs[t * 64 + i];
  float o0 = x0 * cc - x1 * ss;
  float o1 = x0 * ss + x1 * cc;
  u32* pout = reinterpret_cast<u32*>(Kb + ((size_t)(b * HKV_ + kh) * T_ + t) * HD_ + 2 * i);
  *pout = (u32)f2bf(o0) | ((u32)f2bf(o1) << 16);
}

// ---------------- V -> Vh fp16 transposed [B][HKV][HD][T] ----------------
__global__ void k_v_trans(const u16* __restrict__ C1, _Float16* __restrict__ Vh){
  __shared__ float tile[32][33];
  int bz = blockIdx.z;                        // b*8+kh
  int t0 = blockIdx.x * 32, d0 = blockIdx.y * 32;
  int tx = threadIdx.x, ty = threadIdx.y;
  int b = bz >> 3, kh = bz & 7;
  const u16* src = C1 + (size_t)(b * T_) * NQKV + D_ + HKV_ * HD_ + kh * HD_;  // col 5120 + kh*128
  #pragma unroll
  for (int i = ty; i < 32; i += 8)
    tile[i][tx] = bf2f(src[(size_t)(t0 + i) * NQKV + d0 + tx]);
  __syncthreads();
  _Float16* dst = Vh + (size_t)bz * HD_ * T_;
  #pragma unroll
  for (int i = ty; i < 32; i += 8)
    dst[(size_t)(d0 + i) * T_ + t0 + tx] = (_Float16)tile[tx][i];
}

// ---------------- attention: 1 wave per (b, h, 16 q-rows) ----------------
// S^T = K * Q^T via mfma_16x16x32_bf16 (lane: kv=4g+r, q=c)
// PV  via mfma_16x16x16f16, A=P (exact layout match), B=V^T rows
__global__ __launch_bounds__(64) void k_attn(
    const u16* __restrict__ Q,      // C1, (B*T) x NQKV, cols 0..4095 roped
    const u16* __restrict__ Kb,     // [B][HKV][T][HD]
    const _Float16* __restrict__ Vh,// [B][HKV][HD][T]
    u16* __restrict__ Ob)           // (B*T) x 4096
{
  const int l = threadIdx.x;
  const int c = l & 15, g = l >> 4;
  const int q0 = blockIdx.x * 16;
  const int h  = blockIdx.y;
  const int b  = blockIdx.z;
  const int kh = h >> 2;

  const float SCL2 = 0.08838834764831845f * 1.4426950408889634f; // 1/sqrt(128)*log2(e)
  const float OFF2 = 14.4269504f;                                // 10*log2(e)

  const u16* Qrow = Q + (size_t)(b * T_ + q0 + c) * NQKV + h * HD_;
  s16x8 qf[4];
  #pragma unroll
  for (int ci = 0; ci < 4; ci++)
    qf[ci] = *reinterpret_cast<const s16x8*>(Qrow + 32 * ci + 8 * g);

  const u16* Kbase = Kb + (size_t)(b * HKV_ + kh) * T_ * HD_;
  const _Float16* Vc0 = Vh + (size_t)(b * HKV_ + kh) * HD_ * T_ + (size_t)c * T_ + 4 * g;

  f32x4 o[8];
  #pragma unroll
  for (int i = 0; i < 8; i++) o[i] = f32x4{0.f, 0.f, 0.f, 0.f};
  float lsum = 0.f;

  for (int kv0 = 0; kv0 < T_; kv0 += 32) {
    f32x4 s0 = f32x4{0.f,0.f,0.f,0.f}, s1 = f32x4{0.f,0.f,0.f,0.f};
    const u16* Kr0 = Kbase + (size_t)(kv0 + c) * HD_ + 8 * g;
    const u16* Kr1 = Kr0 + 16 * HD_;
    #pragma unroll
    for (int ci = 0; ci < 4; ci++) {
      s16x8 k0f = *reinterpret_cast<const s16x8*>(Kr0 + 32 * ci);
      s16x8 k1f = *reinterpret_cast<const s16x8*>(Kr1 + 32 * ci);
      s0 = __builtin_amdgcn_mfma_f32_16x16x32_bf16(k0f, qf[ci], s0, 0, 0, 0);
      s1 = __builtin_amdgcn_mfma_f32_16x16x32_bf16(k1f, qf[ci], s1, 0, 0, 0);
    }
    f16x4 pa0, pa1;
    #pragma unroll
    for (int r = 0; r < 4; r++) {
      float p0 = exp2f(s0[r] * SCL2 - OFF2);
      float p1 = exp2f(s1[r] * SCL2 - OFF2);
      lsum += p0 + p1;
      pa0[r] = (_Float16)p0;
      pa1[r] = (_Float16)p1;
    }
    #pragma unroll
    for (int dc = 0; dc < 8; dc++) {
      f16x4 v0 = *reinterpret_cast<const f16x4*>(Vc0 + (size_t)(16 * dc) * T_ + kv0);
      f16x4 v1 = *reinterpret_cast<const f16x4*>(Vc0 + (size_t)(16 * dc) * T_ + kv0 + 16);
      o[dc] = __builtin_amdgcn_mfma_f32_16x16x16f16(pa0, v0, o[dc], 0, 0, 0);
      o[dc] = __builtin_amdgcn_mfma_f32_16x16x16f16(pa1, v1, o[dc], 0, 0, 0);
    }
  }

  // total sum per q=c (replicated across groups), then redistribute to q=4g+r
  lsum += __shfl_xor(lsum, 16);
  lsum += __shfl_xor(lsum, 32);
  float inv[4];
  #pragma unroll
  for (int r = 0; r < 4; r++)
    inv[r] = 1.0f / __shfl(lsum, 4 * g + r, 64);

  u16* Orow = Ob + (size_t)(b * T_ + q0) * D_ + h * HD_;
  #pragma unroll
  for (int dc = 0; dc < 8; dc++)
    #pragma unroll
    for (int r = 0; r < 4; r++)
      Orow[(size_t)(4 * g + r) * D_ + 16 * dc + c] = f2bf(o[dc][r] * inv[r]);
}

// ---------------- launch ----------------
extern "C" void kernel_launch(void* const* d_in, const int* in_sizes, int n_in,
                              void* d_out, int out_size, void* d_ws, size_t ws_size,
                              hipStream_t stream)
{
  const float* x  = (const float*)d_in[0];
  const float* fc = (const float*)d_in[1];
  const float* fs = (const float*)d_in[2];
  const float* wq = (const float*)d_in[6];
  const float* wk = (const float*)d_in[7];
  const float* wv = (const float*)d_in[8];
  const float* wo = (const float*)d_in[9];

  unsigned char* w = (unsigned char*)d_ws;
  u16* Xb   = (u16*)(w);                       // 4096x4096 bf16      33,554,432 B
  u16* Wt   = (u16*)(w + 33554432ull);         // 6144x4096 bf16      50,331,648 B
  u16* Wot  = (u16*)(w + 83886080ull);         // 4096x4096 bf16      33,554,432 B
  u16* C1   = (u16*)(w + 117440512ull);        // 4096x6144 bf16      50,331,648 B
  u16* Kb   = (u16*)(w + 167772160ull);        // 2x8x2048x128 bf16    8,388,608 B
  _Float16* Vh = (_Float16*)(w + 176160768ull);// same, fp16 transposed 8,388,608 B
  u16* Ob   = (u16*)(w + 184549376ull);        // 4096x4096 bf16      33,554,432 B
  // total 218,103,808 B

  k_convert_x<<<16384, 256, 0, stream>>>(x, Xb);
  k_transpose_w<<<dim3(128, 128), dim3(32, 8), 0, stream>>>(wq, Wt, D_, D_);
  k_transpose_w<<<dim3(32, 128),  dim3(32, 8), 0, stream>>>(wk, Wt + (size_t)D_ * D_, D_, 1024);
  k_transpose_w<<<dim3(32, 128),  dim3(32, 8), 0, stream>>>(wv, Wt + (size_t)5120 * D_, D_, 1024);
  k_transpose_w<<<dim3(128, 128), dim3(32, 8), 0, stream>>>(wo, Wot, D_, D_);

  k_gemm<0><<<dim3(NQKV / 128, M_ / 128), 256, 0, stream>>>(Xb, Wt, C1, M_, NQKV, D_);

  k_rope_q<<<32768, 256, 0, stream>>>(C1, fc, fs);
  k_rope_k<<<8192, 256, 0, stream>>>(C1, fc, fs, Kb);
  k_v_trans<<<dim3(64, 4, 16), dim3(32, 8), 0, stream>>>(C1, Vh);

  k_attn<<<dim3(T_ / 16, H_, B_), 64, 0, stream>>>(C1, Kb, Vh, Ob);

  k_gemm<1><<<dim3(D_ / 128, M_ / 128), 256, 0, stream>>>(Ob, Wot, d_out, M_, D_, D_);
}

// Round 2
// 630.719 us; speedup vs baseline: 2.9560x; 2.9560x over previous
//
#include <hip/hip_runtime.h>

typedef unsigned short u16;
typedef unsigned int   u32;
typedef __attribute__((ext_vector_type(2))) unsigned int u32x2;
typedef __attribute__((ext_vector_type(4))) float f32x4;
typedef __attribute__((ext_vector_type(8))) short s16x8;
typedef __attribute__((ext_vector_type(4))) _Float16 f16x4;
typedef __attribute__((ext_vector_type(8))) _Float16 f16x8;

#define B_   2
#define T_   2048
#define D_   4096
#define H_   32
#define HKV_ 8
#define HD_  128
#define NQKV 6144
#define M_   (B_*T_)   // 4096

__device__ __forceinline__ u16 f2bf(float f){
  u32 u = __float_as_uint(f);
  u += 0x7fffu + ((u >> 16) & 1u);
  return (u16)(u >> 16);
}
__device__ __forceinline__ float bf2f(u16 h){
  return __uint_as_float(((u32)h) << 16);
}
__device__ __forceinline__ void gload16(const void* g, void* l){
  __builtin_amdgcn_global_load_lds(
      (const __attribute__((address_space(1))) u32*)g,
      (__attribute__((address_space(3))) u32*)l, 16, 0, 0);
}

// ---------------- x: f32 -> bf16 ----------------
__global__ void k_convert_x(const float* __restrict__ in, u16* __restrict__ out){
  int i = blockIdx.x * 256 + threadIdx.x;      // each thread: 4 elems
  float4 v = reinterpret_cast<const float4*>(in)[i];
  u32 lo = (u32)f2bf(v.x) | ((u32)f2bf(v.y) << 16);
  u32 hi = (u32)f2bf(v.z) | ((u32)f2bf(v.w) << 16);
  u32x2 p; p.x = lo; p.y = hi;
  reinterpret_cast<u32x2*>(out)[i] = p;
}

// ---------------- W (K x N f32, k-major) -> Wt (N x K bf16, n-major) ----------------
__global__ void k_transpose_w(const float* __restrict__ in, u16* __restrict__ out,
                              int K, int N){
  __shared__ float tile[32][33];
  int n0 = blockIdx.x * 32, k0 = blockIdx.y * 32;
  int tx = threadIdx.x, ty = threadIdx.y;     // 32 x 8
  #pragma unroll
  for (int i = ty; i < 32; i += 8)
    tile[i][tx] = in[(size_t)(k0 + i) * N + n0 + tx];
  __syncthreads();
  #pragma unroll
  for (int i = ty; i < 32; i += 8)
    out[(size_t)(n0 + i) * K + k0 + tx] = f2bf(tile[tx][i]);
}

// ---------------- GEMM: C[M,N] = A[M,K](bf16) * Wt[N,K](bf16) ----------------
template<int OUT_F32>
__global__ __launch_bounds__(256, 2) void k_gemm(
    const u16* __restrict__ A, const u16* __restrict__ Bt,
    void* __restrict__ Cv, int M, int N, int K)
{
  __shared__ __attribute__((aligned(16))) unsigned char smem[32768];
  unsigned char* As = smem;            // [128 rows][128 B]  (64 bf16/row)
  unsigned char* Bs = smem + 16384;
  const int tid = threadIdx.x;
  const int w = tid >> 6, l = tid & 63;
  const int m0 = blockIdx.y * 128, n0 = blockIdx.x * 128;
  const int wm = (w >> 1) * 64, wn = (w & 1) * 64;
  f32x4 acc[4][4];
  #pragma unroll
  for (int i = 0; i < 4; i++)
    #pragma unroll
    for (int j = 0; j < 4; j++)
      acc[i][j] = f32x4{0.f, 0.f, 0.f, 0.f};

  const int srcoff = 8 * ((l & 7) ^ ((l >> 3) & 7));
  const int subrow = l >> 3;

  for (int k0 = 0; k0 < K; k0 += 64) {
    if (k0) __syncthreads();
    #pragma unroll
    for (int i = 0; i < 4; i++) {
      int chunk = 4 * w + i;
      int row = chunk * 8 + subrow;
      gload16(A  + (size_t)(m0 + row) * K + k0 + srcoff, As + chunk * 1024);
      gload16(Bt + (size_t)(n0 + row) * K + k0 + srcoff, Bs + chunk * 1024);
    }
    asm volatile("s_waitcnt vmcnt(0)" ::: "memory");
    __syncthreads();
    #pragma unroll
    for (int kk = 0; kk < 2; kk++) {
      s16x8 a[4], b[4];
      const int co = kk * 64 + 16 * (l >> 4);
      #pragma unroll
      for (int mi = 0; mi < 4; mi++) {
        int r = wm + 16 * mi + (l & 15);
        a[mi] = *reinterpret_cast<const s16x8*>(As + r * 128 + (co ^ ((r & 7) << 4)));
      }
      #pragma unroll
      for (int ni = 0; ni < 4; ni++) {
        int r = wn + 16 * ni + (l & 15);
        b[ni] = *reinterpret_cast<const s16x8*>(Bs + r * 128 + (co ^ ((r & 7) << 4)));
      }
      #pragma unroll
      for (int mi = 0; mi < 4; mi++)
        #pragma unroll
        for (int ni = 0; ni < 4; ni++)
          acc[mi][ni] = __builtin_amdgcn_mfma_f32_16x16x32_bf16(a[mi], b[ni], acc[mi][ni], 0, 0, 0);
    }
  }
  const int g = l >> 4, c = l & 15;
  #pragma unroll
  for (int mi = 0; mi < 4; mi++)
    #pragma unroll
    for (int ni = 0; ni < 4; ni++)
      #pragma unroll
      for (int r = 0; r < 4; r++) {
        int m = m0 + wm + 16 * mi + 4 * g + r;
        int n = n0 + wn + 16 * ni + c;
        float v = acc[mi][ni][r];
        if (OUT_F32) reinterpret_cast<float*>(Cv)[(size_t)m * N + n] = v;
        else         reinterpret_cast<u16*>(Cv)[(size_t)m * N + n] = f2bf(v);
      }
}

// ---------------- RoPE on Q (in place, cols 0..4095 of C1) ----------------
__global__ void k_rope_q(u16* C1, const float* __restrict__ fc, const float* __restrict__ fs){
  int idx = blockIdx.x * 256 + threadIdx.x;   // M_ * 2048 pairs
  int m = idx >> 11, p = idx & 2047;
  int h = p >> 6, i = p & 63;
  int t = m & (T_ - 1);
  u32* ptr = reinterpret_cast<u32*>(C1 + (size_t)m * NQKV + h * HD_ + 2 * i);
  u32 u = *ptr;
  float x0 = __uint_as_float(u << 16);
  float x1 = __uint_as_float(u & 0xffff0000u);
  float cc = fc[t * 64 + i], ss = fs[t * 64 + i];
  float o0 = x0 * cc - x1 * ss;
  float o1 = x0 * ss + x1 * cc;
  *ptr = (u32)f2bf(o0) | ((u32)f2bf(o1) << 16);
}

// ---- RoPE on K + write PRE-SWIZZLED global layout [b][kh] tiles of [64 rows][256B] ----
// logical byte within 256B row for element d: 2d; stored at chunk(4bits)^=(t&7)
__global__ void k_rope_k(const u16* __restrict__ C1, const float* __restrict__ fc,
                         const float* __restrict__ fs, unsigned char* __restrict__ Kg){
  int idx = blockIdx.x * 256 + threadIdx.x;   // M_ * 512 pairs
  int m = idx >> 9, p = idx & 511;
  int kh = p >> 6, i = p & 63;                // freq index, d = 2i
  int b = m >> 11, t = m & (T_ - 1);
  u32 u = *reinterpret_cast<const u32*>(C1 + (size_t)m * NQKV + D_ + kh * HD_ + 2 * i);
  float x0 = __uint_as_float(u << 16);
  float x1 = __uint_as_float(u & 0xffff0000u);
  float cc = fc[t * 64 + i], ss = fs[t * 64 + i];
  float o0 = x0 * cc - x1 * ss;
  float o1 = x0 * ss + x1 * cc;
  u32 packed = (u32)f2bf(o0) | ((u32)f2bf(o1) << 16);
  unsigned char* Kbb = Kg + (size_t)(b * HKV_ + kh) * 524288;
  int swb = (((i >> 2) ^ (t & 7)) << 4) | (4 * (i & 3));
  *reinterpret_cast<u32*>(Kbb + (size_t)t * 256 + swb) = packed;
}

// ---- V -> fp16 V^T, tile-major [b][kh][T/64][128][64], kv-bit-permuted + swizzled ----
// kv bits [cp][ci1][g1][g0][r1][r0] -> col p bits [cp][g1][g0][ci1][r1][r0]
__global__ void k_v_trans(const u16* __restrict__ C1, unsigned char* __restrict__ Vg){
  __shared__ float tile[32][33];
  int bz = blockIdx.z;                        // b*8+kh
  int t0 = blockIdx.x * 32, d0 = blockIdx.y * 32;
  int tx = threadIdx.x, ty = threadIdx.y;
  int b = bz >> 3, kh = bz & 7;
  const u16* src = C1 + (size_t)(b * T_) * NQKV + D_ + HKV_ * HD_ + kh * HD_;
  #pragma unroll
  for (int i = ty; i < 32; i += 8)
    tile[i][tx] = bf2f(src[(size_t)(t0 + i) * NQKV + d0 + tx]);
  __syncthreads();
  unsigned char* Vbb = Vg + (size_t)bz * 524288;
  #pragma unroll
  for (int i = ty; i < 32; i += 8) {
    int d = d0 + i;
    int k = t0 + tx;
    int tt = k >> 6, kv = k & 63;
    int pp = (kv & 0x23) | ((kv & 0x10) >> 2) | ((kv & 0x0C) << 1);
    int swb = (((pp >> 3) ^ (d & 7)) << 4) | (2 * (pp & 7));
    *reinterpret_cast<_Float16*>(Vbb + (size_t)tt * 16384 + d * 128 + swb) =
        (_Float16)tile[tx][i];
  }
}

// ---------------- attention: 4 waves/block, LDS-staged double-buffered K/V ----------------
// Block = (b, h, 128 q-rows); wave w owns 32 q-rows (2 tiles of 16). KVBLK = 64.
// S^T = K*Q^T via mfma_16x16x32_bf16; PV via mfma_16x16x16f16 with b128 V reads.
__global__ __launch_bounds__(256, 2) void k_attn(
    const u16* __restrict__ Q,              // C1 roped, (B*T) x NQKV
    const unsigned char* __restrict__ Kg,   // pre-swizzled tiles
    const unsigned char* __restrict__ Vg,   // pre-swizzled permuted tiles
    u16* __restrict__ Ob)                   // (B*T) x 4096
{
  __shared__ __attribute__((aligned(16))) unsigned char smem[65536];
  const int tid = threadIdx.x;
  const int w = tid >> 6, l = tid & 63;
  const int c = l & 15, g = l >> 4;
  const int q0 = blockIdx.x * 128 + w * 32;
  const int h = blockIdx.y, b = blockIdx.z;
  const int kh = h >> 2;
  const unsigned char* Kb_ = Kg + (size_t)(b * HKV_ + kh) * 524288;
  const unsigned char* Vb_ = Vg + (size_t)(b * HKV_ + kh) * 524288;

  const float SCL2 = 0.08838834764831845f * 1.4426950408889634f; // 1/sqrt(128)*log2e
  const float OFF2 = 14.4269504f;                                // 10*log2e

  s16x8 qf[2][4];
  #pragma unroll
  for (int qt = 0; qt < 2; qt++)
    #pragma unroll
    for (int ci = 0; ci < 4; ci++)
      qf[qt][ci] = *reinterpret_cast<const s16x8*>(
          Q + (size_t)(b * T_ + q0 + 16 * qt + c) * NQKV + h * HD_ + 32 * ci + 8 * g);

  f32x4 o[2][8];
  #pragma unroll
  for (int qt = 0; qt < 2; qt++)
    #pragma unroll
    for (int i = 0; i < 8; i++) o[qt][i] = f32x4{0.f, 0.f, 0.f, 0.f};
  float lsum[2] = {0.f, 0.f};

  // stage one 16KB K tile + 16KB V tile (linear copy; swizzle pre-baked in global)
  auto stage = [&](int bi, int tt) {
    const unsigned char* Ks = Kb_ + (size_t)tt * 16384;
    const unsigned char* Vs = Vb_ + (size_t)tt * 16384;
    unsigned char* Kl = smem + bi * 32768;
    unsigned char* Vl = Kl + 16384;
    #pragma unroll
    for (int i = 0; i < 4; i++) {
      int ch = i * 4 + w;
      gload16(Ks + ch * 1024 + l * 16, Kl + ch * 1024);
      gload16(Vs + ch * 1024 + l * 16, Vl + ch * 1024);
    }
  };

  stage(0, 0);
  asm volatile("s_waitcnt vmcnt(0)" ::: "memory");
  __syncthreads();

  for (int tt = 0; tt < T_ / 64; ++tt) {
    int cur = tt & 1;
    if (tt < T_ / 64 - 1) stage(cur ^ 1, tt + 1);
    const unsigned char* Kl = smem + cur * 32768;
    const unsigned char* Vl = Kl + 16384;

    f32x4 s[4][2];
    #pragma unroll
    for (int mi = 0; mi < 4; mi++)
      #pragma unroll
      for (int qt = 0; qt < 2; qt++) s[mi][qt] = f32x4{0.f, 0.f, 0.f, 0.f};

    #pragma unroll
    for (int mi = 0; mi < 4; mi++) {
      const int row = 16 * mi + c;
      const int sw = (row & 7) << 4;
      s16x8 kf[4];
      #pragma unroll
      for (int ci = 0; ci < 4; ci++)
        kf[ci] = *reinterpret_cast<const s16x8*>(Kl + row * 256 + ((64 * ci + 16 * g) ^ sw));
      #pragma unroll
      for (int qt = 0; qt < 2; qt++)
        #pragma unroll
        for (int ci = 0; ci < 4; ci++)
          s[mi][qt] = __builtin_amdgcn_mfma_f32_16x16x32_bf16(kf[ci], qf[qt][ci], s[mi][qt], 0, 0, 0);
    }

    f16x4 pa[2][4];
    #pragma unroll
    for (int qt = 0; qt < 2; qt++)
      #pragma unroll
      for (int mi = 0; mi < 4; mi++)
        #pragma unroll
        for (int r = 0; r < 4; r++) {
          float p = exp2f(s[mi][qt][r] * SCL2 - OFF2);
          lsum[qt] += p;
          pa[qt][mi][r] = (_Float16)p;
        }

    #pragma unroll
    for (int cp = 0; cp < 2; cp++)
      #pragma unroll
      for (int dc = 0; dc < 8; dc++) {
        const int d = 16 * dc + c;
        f16x8 v8 = *reinterpret_cast<const f16x8*>(
            Vl + d * 128 + ((64 * cp + 16 * g) ^ ((d & 7) << 4)));
        f16x4 lo = {v8[0], v8[1], v8[2], v8[3]};
        f16x4 hi = {v8[4], v8[5], v8[6], v8[7]};
        #pragma unroll
        for (int qt = 0; qt < 2; qt++) {
          o[qt][dc] = __builtin_amdgcn_mfma_f32_16x16x16f16(pa[qt][2 * cp], lo, o[qt][dc], 0, 0, 0);
          o[qt][dc] = __builtin_amdgcn_mfma_f32_16x16x16f16(pa[qt][2 * cp + 1], hi, o[qt][dc], 0, 0, 0);
        }
      }

    asm volatile("s_waitcnt vmcnt(0)" ::: "memory");
    __syncthreads();
  }

  #pragma unroll
  for (int qt = 0; qt < 2; qt++) {
    lsum[qt] += __shfl_xor(lsum[qt], 16);
    lsum[qt] += __shfl_xor(lsum[qt], 32);
  }
  float inv[2][4];
  #pragma unroll
  for (int qt = 0; qt < 2; qt++)
    #pragma unroll
    for (int r = 0; r < 4; r++)
      inv[qt][r] = 1.0f / __shfl(lsum[qt], 4 * g + r, 64);

  #pragma unroll
  for (int qt = 0; qt < 2; qt++) {
    u16* Orow = Ob + (size_t)(b * T_ + q0 + 16 * qt) * D_ + h * HD_;
    #pragma unroll
    for (int dc = 0; dc < 8; dc++)
      #pragma unroll
      for (int r = 0; r < 4; r++)
        Orow[(size_t)(4 * g + r) * D_ + 16 * dc + c] = f2bf(o[qt][dc][r] * inv[qt][r]);
  }
}

// ---------------- launch ----------------
extern "C" void kernel_launch(void* const* d_in, const int* in_sizes, int n_in,
                              void* d_out, int out_size, void* d_ws, size_t ws_size,
                              hipStream_t stream)
{
  const float* x  = (const float*)d_in[0];
  const float* fc = (const float*)d_in[1];
  const float* fs = (const float*)d_in[2];
  const float* wq = (const float*)d_in[6];
  const float* wk = (const float*)d_in[7];
  const float* wv = (const float*)d_in[8];
  const float* wo = (const float*)d_in[9];

  unsigned char* w = (unsigned char*)d_ws;
  u16* Xb   = (u16*)(w);                       // 4096x4096 bf16      33,554,432 B
  u16* Wt   = (u16*)(w + 33554432ull);         // 6144x4096 bf16      50,331,648 B
  u16* Wot  = (u16*)(w + 83886080ull);         // 4096x4096 bf16      33,554,432 B
  u16* C1   = (u16*)(w + 117440512ull);        // 4096x6144 bf16      50,331,648 B
  unsigned char* Kg = w + 167772160ull;        // 16 x 512KB swizzled  8,388,608 B
  unsigned char* Vg = w + 176160768ull;        // 16 x 512KB swizzled  8,388,608 B
  u16* Ob   = (u16*)(w + 184549376ull);        // 4096x4096 bf16      33,554,432 B

  k_convert_x<<<16384, 256, 0, stream>>>(x, Xb);
  k_transpose_w<<<dim3(128, 128), dim3(32, 8), 0, stream>>>(wq, Wt, D_, D_);
  k_transpose_w<<<dim3(32, 128),  dim3(32, 8), 0, stream>>>(wk, Wt + (size_t)D_ * D_, D_, 1024);
  k_transpose_w<<<dim3(32, 128),  dim3(32, 8), 0, stream>>>(wv, Wt + (size_t)5120 * D_, D_, 1024);
  k_transpose_w<<<dim3(128, 128), dim3(32, 8), 0, stream>>>(wo, Wot, D_, D_);

  k_gemm<0><<<dim3(NQKV / 128, M_ / 128), 256, 0, stream>>>(Xb, Wt, C1, M_, NQKV, D_);

  k_rope_q<<<32768, 256, 0, stream>>>(C1, fc, fs);
  k_rope_k<<<8192, 256, 0, stream>>>(C1, fc, fs, Kg);
  k_v_trans<<<dim3(64, 4, 16), dim3(32, 8), 0, stream>>>(C1, Vg);

  k_attn<<<dim3(T_ / 128, H_, B_), 256, 0, stream>>>(C1, Kg, Vg, Ob);

  k_gemm<1><<<dim3(D_ / 128, M_ / 128), 256, 0, stream>>>(Ob, Wot, d_out, M_, D_, D_);
}